// Round 1
// baseline (3469.311 us; speedup 1.0000x reference)
//
#include <hip/hip_runtime.h>
#include <hip/hip_bf16.h>

// Problem constants (match reference).
#define N_NODES 50000
#define N_PER   12500
#define E_EDGES 600000
#define HDIM    128

// Native fp32 global atomic add (global_atomic_add_f32). Plain atomicAdd(float*)
// may lower to a CAS loop without -munsafe-fp-atomics.
__device__ __forceinline__ void atomAddF(float* p, float v) {
    unsafeAtomicAdd(p, v);
}

// ---------------------------------------------------------------------------
// Degree accumulation: deg_out[src[i]] += 1, deg_in[dst[i]] += 1
// ---------------------------------------------------------------------------
__global__ void deg_kernel(const int* __restrict__ src, const int* __restrict__ dst,
                           float* __restrict__ deg_out, float* __restrict__ deg_in) {
    int i = blockIdx.x * blockDim.x + threadIdx.x;
    if (i < E_EDGES) {
        atomAddF(&deg_out[src[i]], 1.0f);
        atomAddF(&deg_in[dst[i]], 1.0f);
    }
}

// In-place: x -> rsqrt(max(x,1)) for both norm arrays.
__global__ void norm_kernel(float* __restrict__ a, float* __restrict__ b) {
    int i = blockIdx.x * blockDim.x + threadIdx.x;
    if (i < N_NODES) {
        a[i] = rsqrtf(fmaxf(a[i], 1.0f));
        b[i] = rsqrtf(fmaxf(b[i], 1.0f));
    }
}

// ---------------------------------------------------------------------------
// Row GEMM: out[r, j] = post( dot(X[r,:], W[:,j]) * s1[r] + bias[j] ) * s2[r]
//   s1 / s2 may be null (treated as 1). RELU applied after bias if requested.
// Block = 256 threads = 2 rows x 128 cols; 8 rows per block; W staged in LDS
// as 64-row k-tiles (32KB) -> 34KB LDS total.
// ---------------------------------------------------------------------------
template <int D, bool RELU>
__global__ __launch_bounds__(256) void rowmm_kernel(
    const float* __restrict__ X,    // [rows, D]
    const float* __restrict__ W,    // [D, 128] row-major
    const float* __restrict__ bias, // [128]
    const float* __restrict__ s1,   // [rows] or null
    const float* __restrict__ s2,   // [rows] or null
    float* __restrict__ out,        // [rows, 128]
    int rows)
{
    constexpr int KT  = 64;  // k-tile rows of W staged at a time
    constexpr int NPB = 8;   // node rows per block
    __shared__ float Wl[KT * 128];   // 32 KB
    __shared__ float Xl[NPB][KT];    // 2 KB

    const int tid  = threadIdx.x;
    const int half = tid >> 7;       // 0 or 1
    const int j    = tid & 127;
    const int base = blockIdx.x * NPB;

    float acc[NPB / 2];
    for (int r = 0; r < NPB / 2; ++r) acc[r] = 0.0f;

    for (int kt = 0; kt < D; kt += KT) {
        __syncthreads();
        // Stage W k-tile (KT x 128) -- coalesced.
        for (int idx = tid; idx < KT * 128; idx += 256)
            Wl[idx] = W[kt * 128 + idx];
        // Stage X tile (NPB x KT).
        for (int idx = tid; idx < NPB * KT; idx += 256) {
            int rr = idx / KT, kk = idx % KT;
            int r = base + rr;
            Xl[rr][kk] = (r < rows) ? X[r * D + kt + kk] : 0.0f;
        }
        __syncthreads();

        for (int rr = 0; rr < NPB / 2; ++rr) {
            float a = 0.0f;
            const float* xr = Xl[rr * 2 + half];
#pragma unroll 8
            for (int k = 0; k < KT; ++k)
                a += xr[k] * Wl[k * 128 + j];   // X broadcast; W 2-way bank alias (free)
            acc[rr] += a;
        }
    }

    const float bj = bias[j];
    for (int rr = 0; rr < NPB / 2; ++rr) {
        int r = base + rr * 2 + half;
        if (r < rows) {
            float v = acc[rr];
            if (s1) v *= s1[r];
            v += bj;
            if (RELU) v = fmaxf(v, 0.0f);
            if (s2) v *= s2[r];
            out[r * 128 + j] = v;
        }
    }
}

// ---------------------------------------------------------------------------
// GCN aggregation: B[dst[e], :] += A[src[e], :]   (A already carries out_norm)
// 32 threads per edge, float4 per thread (128 floats/row).
// ---------------------------------------------------------------------------
__global__ void agg_kernel(const float4* __restrict__ A4,
                           const int* __restrict__ src, const int* __restrict__ dst,
                           float* __restrict__ B) {
    int idx = blockIdx.x * blockDim.x + threadIdx.x;
    int e = idx >> 5;
    if (e >= E_EDGES) return;
    int j4 = idx & 31;
    int s = src[e], d = dst[e];
    float4 v = A4[s * 32 + j4];
    float* bp = &B[d * 128 + j4 * 4];
    atomAddF(bp + 0, v.x);
    atomAddF(bp + 1, v.y);
    atomAddF(bp + 2, v.z);
    atomAddF(bp + 3, v.w);
}

// Layer-0 epilogue: A = relu(B * in_norm + b_g0) * out_norm  (elementwise)
__global__ void relu_scale_kernel(const float* __restrict__ B,
                                  const float* __restrict__ in_norm,
                                  const float* __restrict__ b_g0,
                                  const float* __restrict__ out_norm,
                                  float* __restrict__ A) {
    int idx = blockIdx.x * blockDim.x + threadIdx.x;
    if (idx < N_NODES * HDIM) {
        int i = idx >> 7, j = idx & 127;
        A[idx] = fmaxf(B[idx] * in_norm[i] + b_g0[j], 0.0f) * out_norm[i];
    }
}

// ---------------------------------------------------------------------------
// Final edge-typed aggregation:
//   out[dst] += h[src] * (e in {0..4} ? 2 : 1)
//   out[src] += h[dst] * (e in {6,14,30} ? 1 : 0)
// ---------------------------------------------------------------------------
__global__ void final_kernel(const float4* __restrict__ A4,
                             const int* __restrict__ src, const int* __restrict__ dst,
                             const int* __restrict__ efeat,
                             float* __restrict__ out) {
    int idx = blockIdx.x * blockDim.x + threadIdx.x;
    int e = idx >> 5;
    if (e >= E_EDGES) return;
    int j4 = idx & 31;
    int s = src[e], d = dst[e], t = efeat[e];
    float wf = (t >= 0 && t <= 4) ? 2.0f : 1.0f;
    float4 v = A4[s * 32 + j4];
    float* op = &out[d * 128 + j4 * 4];
    atomAddF(op + 0, v.x * wf);
    atomAddF(op + 1, v.y * wf);
    atomAddF(op + 2, v.z * wf);
    atomAddF(op + 3, v.w * wf);
    if (t == 6 || t == 14 || t == 30) {
        float4 u = A4[d * 32 + j4];
        float* op2 = &out[s * 128 + j4 * 4];
        atomAddF(op2 + 0, u.x);
        atomAddF(op2 + 1, u.y);
        atomAddF(op2 + 2, u.z);
        atomAddF(op2 + 3, u.w);
    }
}

extern "C" void kernel_launch(void* const* d_in, const int* in_sizes, int n_in,
                              void* d_out, int out_size, void* d_ws, size_t ws_size,
                              hipStream_t stream) {
    // setup_inputs() dict order (interleaved per type!):
    const float* feat[4]  = {(const float*)d_in[0], (const float*)d_in[3],
                             (const float*)d_in[6], (const float*)d_in[9]};
    const float* W_fc[4]  = {(const float*)d_in[1], (const float*)d_in[4],
                             (const float*)d_in[7], (const float*)d_in[10]};
    const float* b_fc[4]  = {(const float*)d_in[2], (const float*)d_in[5],
                             (const float*)d_in[8], (const float*)d_in[11]};
    const int*   src      = (const int*)d_in[12];
    const int*   dst      = (const int*)d_in[13];
    const int*   efeat    = (const int*)d_in[14];
    const float* b_g0     = (const float*)d_in[15];
    const float* W_g1     = (const float*)d_in[16];
    const float* b_g1     = (const float*)d_in[17];
    float* out = (float*)d_out;

    // Workspace layout: A[6.4M f32] | B[6.4M f32] | out_norm[50k] | in_norm[50k]
    float* A        = (float*)d_ws;
    float* B        = A + (size_t)N_NODES * HDIM;
    float* out_norm = B + (size_t)N_NODES * HDIM;
    float* in_norm  = out_norm + N_NODES;

    const size_t buf_bytes = (size_t)N_NODES * HDIM * sizeof(float);

    // 1) degrees -> norms (accumulate degrees directly into norm arrays)
    hipMemsetAsync(out_norm, 0, 2 * (size_t)N_NODES * sizeof(float), stream);
    deg_kernel<<<(E_EDGES + 255) / 256, 256, 0, stream>>>(src, dst, out_norm, in_norm);
    norm_kernel<<<(N_NODES + 255) / 256, 256, 0, stream>>>(out_norm, in_norm);

    // 2) per-type FC: A[type rows] = (feat @ W + b) * out_norm
    const int grid_fc = (N_PER + 7) / 8;
    rowmm_kernel<128, false><<<grid_fc, 256, 0, stream>>>(
        feat[0], W_fc[0], b_fc[0], nullptr, out_norm + 0 * N_PER,
        A + (size_t)0 * N_PER * HDIM, N_PER);
    rowmm_kernel<128, false><<<grid_fc, 256, 0, stream>>>(
        feat[1], W_fc[1], b_fc[1], nullptr, out_norm + 1 * N_PER,
        A + (size_t)1 * N_PER * HDIM, N_PER);
    rowmm_kernel<64, false><<<grid_fc, 256, 0, stream>>>(
        feat[2], W_fc[2], b_fc[2], nullptr, out_norm + 2 * N_PER,
        A + (size_t)2 * N_PER * HDIM, N_PER);
    rowmm_kernel<64, false><<<grid_fc, 256, 0, stream>>>(
        feat[3], W_fc[3], b_fc[3], nullptr, out_norm + 3 * N_PER,
        A + (size_t)3 * N_PER * HDIM, N_PER);

    const int grid_edge = (E_EDGES * 32 + 255) / 256;

    // 3) GCN layer 0 aggregation: B = segsum(A[src] -> dst)
    hipMemsetAsync(B, 0, buf_bytes, stream);
    agg_kernel<<<grid_edge, 256, 0, stream>>>((const float4*)A, src, dst, B);
    // A = relu(B * in_norm + b_g0) * out_norm   (pre-scaled for next layer)
    relu_scale_kernel<<<(N_NODES * HDIM + 255) / 256, 256, 0, stream>>>(
        B, in_norm, b_g0, out_norm, A);

    // 4) GCN layer 1 aggregation: B = segsum(A[src] -> dst)
    hipMemsetAsync(B, 0, buf_bytes, stream);
    agg_kernel<<<grid_edge, 256, 0, stream>>>((const float4*)A, src, dst, B);
    // A = relu((B @ W_g1) * in_norm + b_g1)
    rowmm_kernel<128, true><<<(N_NODES + 7) / 8, 256, 0, stream>>>(
        B, W_g1, b_g1, in_norm, nullptr, A, N_NODES);

    // 5) final edge-typed aggregation into d_out
    hipMemsetAsync(out, 0, buf_bytes, stream);
    final_kernel<<<grid_edge, 256, 0, stream>>>((const float4*)A, src, dst, efeat, out);
}

// Round 2
// 639.443 us; speedup vs baseline: 5.4255x; 5.4255x over previous
//
#include <hip/hip_runtime.h>
#include <hip/hip_bf16.h>

#define N_NODES 50000
#define N_PER   12500
#define E_EDGES 600000
#define HDIM    128

__device__ __forceinline__ void atomAddF(float* p, float v) { unsafeAtomicAdd(p, v); }

// ---------------------------------------------------------------------------
// Count kernel: deg_in[dst]++, deg_out[src]++, cnt_bwd[src]++ if t in {6,14,30}
// ---------------------------------------------------------------------------
__global__ void count_kernel(const int* __restrict__ src, const int* __restrict__ dst,
                             const int* __restrict__ ef,
                             int* __restrict__ deg_in, int* __restrict__ deg_out,
                             int* __restrict__ cnt_bwd) {
    int e = blockIdx.x * blockDim.x + threadIdx.x;
    if (e >= E_EDGES) return;
    int s = src[e], d = dst[e], t = ef[e];
    atomicAdd(&deg_in[d], 1);
    atomicAdd(&deg_out[s], 1);
    if (t == 6 || t == 14 || t == 30) atomicAdd(&cnt_bwd[s], 1);
}

// ---------------------------------------------------------------------------
// Single-workgroup exclusive scan of TWO int arrays (n=50000), writing offsets
// (n+1 entries, off[n]=total) and a cursor copy of the offsets.
// ---------------------------------------------------------------------------
__global__ __launch_bounds__(1024) void scan_two_kernel(
    const int* __restrict__ a, const int* __restrict__ b,
    int* __restrict__ offa, int* __restrict__ offb,
    int* __restrict__ cura, int* __restrict__ curb, int n) {
    __shared__ int sa[1024];
    __shared__ int sb[1024];
    const int tid = threadIdx.x;
    int carry_a = 0, carry_b = 0;
    for (int base = 0; base < n; base += 1024) {
        int i = base + tid;
        int va = (i < n) ? a[i] : 0;
        int vb = (i < n) ? b[i] : 0;
        sa[tid] = va; sb[tid] = vb;
        __syncthreads();
        for (int off = 1; off < 1024; off <<= 1) {
            int ta = (tid >= off) ? sa[tid - off] : 0;
            int tb = (tid >= off) ? sb[tid - off] : 0;
            __syncthreads();
            sa[tid] += ta; sb[tid] += tb;
            __syncthreads();
        }
        if (i < n) {
            int ea = carry_a + (tid ? sa[tid - 1] : 0);
            int eb = carry_b + (tid ? sb[tid - 1] : 0);
            offa[i] = ea; cura[i] = ea;
            offb[i] = eb; curb[i] = eb;
        }
        carry_a += sa[1023];
        carry_b += sb[1023];
        __syncthreads();
    }
    if (tid == 0) { offa[n] = carry_a; offb[n] = carry_b; }
}

// norms from int degrees
__global__ void norm_from_deg_kernel(const int* __restrict__ dout, const int* __restrict__ din,
                                     float* __restrict__ onrm, float* __restrict__ inrm) {
    int i = blockIdx.x * blockDim.x + threadIdx.x;
    if (i < N_NODES) {
        onrm[i] = rsqrtf(fmaxf((float)dout[i], 1.0f));
        inrm[i] = rsqrtf(fmaxf((float)din[i], 1.0f));
    }
}

// ---------------------------------------------------------------------------
// Fill CSR: forward list keyed by dst (src id packed with weight bit31),
// backward list keyed by src (only t in {6,14,30}), storing dst id.
// ---------------------------------------------------------------------------
__global__ void fill_kernel(const int* __restrict__ src, const int* __restrict__ dst,
                            const int* __restrict__ ef,
                            int* __restrict__ cur_in, int* __restrict__ cur_bwd,
                            int* __restrict__ csr_src, int* __restrict__ csr_bnode) {
    int e = blockIdx.x * blockDim.x + threadIdx.x;
    if (e >= E_EDGES) return;
    int s = src[e], d = dst[e], t = ef[e];
    int p = atomicAdd(&cur_in[d], 1);
    csr_src[p] = s | ((t <= 4) ? 0x80000000 : 0);   // bit31: forward weight == 2
    if (t == 6 || t == 14 || t == 30) {
        int q = atomicAdd(&cur_bwd[s], 1);
        csr_bnode[q] = d;
    }
}

// ---------------------------------------------------------------------------
// Row GEMM (unchanged from R0): out[r,j] = post(dot(X[r,:],W[:,j])*s1 + b)*s2
// ---------------------------------------------------------------------------
template <int D, bool RELU>
__global__ __launch_bounds__(256) void rowmm_kernel(
    const float* __restrict__ X, const float* __restrict__ W,
    const float* __restrict__ bias, const float* __restrict__ s1,
    const float* __restrict__ s2, float* __restrict__ out, int rows)
{
    constexpr int KT  = 64;
    constexpr int NPB = 8;
    __shared__ float Wl[KT * 128];
    __shared__ float Xl[NPB][KT];

    const int tid  = threadIdx.x;
    const int half = tid >> 7;
    const int j    = tid & 127;
    const int base = blockIdx.x * NPB;

    float acc[NPB / 2];
    for (int r = 0; r < NPB / 2; ++r) acc[r] = 0.0f;

    for (int kt = 0; kt < D; kt += KT) {
        __syncthreads();
        for (int idx = tid; idx < KT * 128; idx += 256)
            Wl[idx] = W[kt * 128 + idx];
        for (int idx = tid; idx < NPB * KT; idx += 256) {
            int rr = idx / KT, kk = idx % KT;
            int r = base + rr;
            Xl[rr][kk] = (r < rows) ? X[r * D + kt + kk] : 0.0f;
        }
        __syncthreads();

        for (int rr = 0; rr < NPB / 2; ++rr) {
            float a = 0.0f;
            const float* xr = Xl[rr * 2 + half];
#pragma unroll 8
            for (int k = 0; k < KT; ++k)
                a += xr[k] * Wl[k * 128 + j];
            acc[rr] += a;
        }
    }

    const float bj = bias[j];
    for (int rr = 0; rr < NPB / 2; ++rr) {
        int r = base + rr * 2 + half;
        if (r < rows) {
            float v = acc[rr];
            if (s1) v *= s1[r];
            v += bj;
            if (RELU) v = fmaxf(v, 0.0f);
            if (s2) v *= s2[r];
            out[r * 128 + j] = v;
        }
    }
}

// ---------------------------------------------------------------------------
// Gather aggregation, layer 0 (fused epilogue):
//   B[n] = relu(sum_{e in in(n)} A[src_e] * in_norm[n] + b_g0) * out_norm[n]
// 32 lanes per node, float4 per lane.
// ---------------------------------------------------------------------------
__global__ __launch_bounds__(256) void agg0_kernel(
    const float4* __restrict__ A4, const int* __restrict__ off,
    const int* __restrict__ csr, const float* __restrict__ in_norm,
    const float* __restrict__ b_g0, const float* __restrict__ out_norm,
    float4* __restrict__ B4) {
    int idx = blockIdx.x * blockDim.x + threadIdx.x;
    int n = idx >> 5;
    if (n >= N_NODES) return;
    int j4 = idx & 31;
    int e0 = off[n], e1 = off[n + 1];
    float4 acc = {0.f, 0.f, 0.f, 0.f};
    for (int e = e0; e < e1; ++e) {
        int s = csr[e] & 0x7fffffff;
        float4 v = A4[(size_t)s * 32 + j4];
        acc.x += v.x; acc.y += v.y; acc.z += v.z; acc.w += v.w;
    }
    float innv = in_norm[n], onv = out_norm[n];
    const float4 bg = ((const float4*)b_g0)[j4];
    float4 r;
    r.x = fmaxf(acc.x * innv + bg.x, 0.f) * onv;
    r.y = fmaxf(acc.y * innv + bg.y, 0.f) * onv;
    r.z = fmaxf(acc.z * innv + bg.z, 0.f) * onv;
    r.w = fmaxf(acc.w * innv + bg.w, 0.f) * onv;
    B4[(size_t)n * 32 + j4] = r;
}

// Gather aggregation, plain: B[n] = sum A[src_e]
__global__ __launch_bounds__(256) void agg1_kernel(
    const float4* __restrict__ A4, const int* __restrict__ off,
    const int* __restrict__ csr, float4* __restrict__ B4) {
    int idx = blockIdx.x * blockDim.x + threadIdx.x;
    int n = idx >> 5;
    if (n >= N_NODES) return;
    int j4 = idx & 31;
    int e0 = off[n], e1 = off[n + 1];
    float4 acc = {0.f, 0.f, 0.f, 0.f};
    for (int e = e0; e < e1; ++e) {
        int s = csr[e] & 0x7fffffff;
        float4 v = A4[(size_t)s * 32 + j4];
        acc.x += v.x; acc.y += v.y; acc.z += v.z; acc.w += v.w;
    }
    B4[(size_t)n * 32 + j4] = acc;
}

// ---------------------------------------------------------------------------
// Final gather: out[n] = sum_{fwd in(n)} h[src]*wf + sum_{bwd list(n)} h[dst]
// ---------------------------------------------------------------------------
__global__ __launch_bounds__(256) void final_gather_kernel(
    const float4* __restrict__ H4,
    const int* __restrict__ off_in, const int* __restrict__ csr_src,
    const int* __restrict__ off_bwd, const int* __restrict__ csr_bnode,
    float4* __restrict__ out4) {
    int idx = blockIdx.x * blockDim.x + threadIdx.x;
    int n = idx >> 5;
    if (n >= N_NODES) return;
    int j4 = idx & 31;
    float4 acc = {0.f, 0.f, 0.f, 0.f};
    int e0 = off_in[n], e1 = off_in[n + 1];
    for (int e = e0; e < e1; ++e) {
        int c = csr_src[e];
        int s = c & 0x7fffffff;
        float w = (c < 0) ? 2.0f : 1.0f;
        float4 v = H4[(size_t)s * 32 + j4];
        acc.x += v.x * w; acc.y += v.y * w; acc.z += v.z * w; acc.w += v.w * w;
    }
    int f0 = off_bwd[n], f1 = off_bwd[n + 1];
    for (int e = f0; e < f1; ++e) {
        int d = csr_bnode[e];
        float4 v = H4[(size_t)d * 32 + j4];
        acc.x += v.x; acc.y += v.y; acc.z += v.z; acc.w += v.w;
    }
    out4[(size_t)n * 32 + j4] = acc;
}

extern "C" void kernel_launch(void* const* d_in, const int* in_sizes, int n_in,
                              void* d_out, int out_size, void* d_ws, size_t ws_size,
                              hipStream_t stream) {
    const float* feat[4]  = {(const float*)d_in[0], (const float*)d_in[3],
                             (const float*)d_in[6], (const float*)d_in[9]};
    const float* W_fc[4]  = {(const float*)d_in[1], (const float*)d_in[4],
                             (const float*)d_in[7], (const float*)d_in[10]};
    const float* b_fc[4]  = {(const float*)d_in[2], (const float*)d_in[5],
                             (const float*)d_in[8], (const float*)d_in[11]};
    const int*   src      = (const int*)d_in[12];
    const int*   dst      = (const int*)d_in[13];
    const int*   efeat    = (const int*)d_in[14];
    const float* b_g0     = (const float*)d_in[15];
    const float* W_g1     = (const float*)d_in[16];
    const float* b_g1     = (const float*)d_in[17];
    float* out = (float*)d_out;

    // Workspace layout (floats then ints), ~58 MB total.
    float* A        = (float*)d_ws;                       // 6.4M
    float* B        = A + (size_t)N_NODES * HDIM;         // 6.4M
    float* out_norm = B + (size_t)N_NODES * HDIM;         // 50k
    float* in_norm  = out_norm + N_NODES;                 // 50k
    int* deg_in    = (int*)(in_norm + N_NODES);           // 50k
    int* deg_out   = deg_in + N_NODES;                    // 50k
    int* cnt_bwd   = deg_out + N_NODES;                   // 50k
    int* off_in    = cnt_bwd + N_NODES;                   // 50k+1
    int* off_bwd   = off_in + N_NODES + 1;                // 50k+1
    int* cur_in    = off_bwd + N_NODES + 1;               // 50k
    int* cur_bwd   = cur_in + N_NODES;                    // 50k
    int* csr_src   = cur_bwd + N_NODES;                   // 600k
    int* csr_bnode = csr_src + E_EDGES;                   // 600k

    // 1) CSR build
    hipMemsetAsync(deg_in, 0, 3 * (size_t)N_NODES * sizeof(int), stream);
    count_kernel<<<(E_EDGES + 255) / 256, 256, 0, stream>>>(src, dst, efeat,
                                                            deg_in, deg_out, cnt_bwd);
    scan_two_kernel<<<1, 1024, 0, stream>>>(deg_in, cnt_bwd, off_in, off_bwd,
                                            cur_in, cur_bwd, N_NODES);
    norm_from_deg_kernel<<<(N_NODES + 255) / 256, 256, 0, stream>>>(deg_out, deg_in,
                                                                    out_norm, in_norm);
    fill_kernel<<<(E_EDGES + 255) / 256, 256, 0, stream>>>(src, dst, efeat,
                                                           cur_in, cur_bwd,
                                                           csr_src, csr_bnode);

    // 2) per-type FC: A = (feat @ W + b) * out_norm
    const int grid_fc = (N_PER + 7) / 8;
    rowmm_kernel<128, false><<<grid_fc, 256, 0, stream>>>(
        feat[0], W_fc[0], b_fc[0], nullptr, out_norm + 0 * N_PER,
        A + (size_t)0 * N_PER * HDIM, N_PER);
    rowmm_kernel<128, false><<<grid_fc, 256, 0, stream>>>(
        feat[1], W_fc[1], b_fc[1], nullptr, out_norm + 1 * N_PER,
        A + (size_t)1 * N_PER * HDIM, N_PER);
    rowmm_kernel<64, false><<<grid_fc, 256, 0, stream>>>(
        feat[2], W_fc[2], b_fc[2], nullptr, out_norm + 2 * N_PER,
        A + (size_t)2 * N_PER * HDIM, N_PER);
    rowmm_kernel<64, false><<<grid_fc, 256, 0, stream>>>(
        feat[3], W_fc[3], b_fc[3], nullptr, out_norm + 3 * N_PER,
        A + (size_t)3 * N_PER * HDIM, N_PER);

    const int grid_node = (N_NODES * 32 + 255) / 256;

    // 3) layer0: gather A -> epilogue -> B (pre-scaled by out_norm for layer1)
    agg0_kernel<<<grid_node, 256, 0, stream>>>((const float4*)A, off_in, csr_src,
                                               in_norm, b_g0, out_norm, (float4*)B);
    // 4) layer1: gather B -> A (raw), then rowmm: B = relu((A @ W_g1)*in_norm + b_g1)
    agg1_kernel<<<grid_node, 256, 0, stream>>>((const float4*)B, off_in, csr_src,
                                               (float4*)A);
    rowmm_kernel<128, true><<<(N_NODES + 7) / 8, 256, 0, stream>>>(
        A, W_g1, b_g1, in_norm, nullptr, B, N_NODES);

    // 5) final edge-typed gather into d_out (writes every element; no memset)
    final_gather_kernel<<<grid_node, 256, 0, stream>>>((const float4*)B,
                                                       off_in, csr_src,
                                                       off_bwd, csr_bnode,
                                                       (float4*)out);
}